// Round 4
// baseline (521.324 us; speedup 1.0000x reference)
//
#include <hip/hip_runtime.h>
#include <hip/hip_cooperative_groups.h>

namespace cg = cooperative_groups;

#define NBINS 256
#define NCHAN 192                 // 64*3 channels
#define BPC 8                     // blocks per channel
#define TPB 256                   // 4 waves/block
#define NCOPY 16                  // bank-replicated LDS hist copies (16 KiB)
#define VPB 8192                  // float4 per block-strip (32768 px)

typedef float f4 __attribute__((ext_vector_type(4)));

// Phase A: stream this block's strip of x, clamp->u8, histogram into
// bank-replicated LDS (lanes 4k..4k+3 -> copy k; bank = copy + 16*(bin&1):
// ~2 lanes/bank expected on random bins = free per m136). Plain-store the
// 256-bin partial (no zeroing, no global atomics needed).
__device__ __forceinline__ void phaseA_hist(const float* __restrict__ x,
                                            int* __restrict__ partials,
                                            int* lh) {
    const int tid = threadIdx.x;
    const int cp  = (tid & 63) >> 2;

    for (int i = tid; i < NBINS * NCOPY; i += TPB) lh[i] = 0;
    __syncthreads();

    const size_t base = (size_t)blockIdx.x * VPB;
    const f4* bx = (const f4*)x + base;

    #pragma unroll 4
    for (int i = tid; i < VPB; i += TPB) {
        f4 v = bx[i];
        int a = (int)fminf(fmaxf(v.x, 0.f), 255.f);
        int b = (int)fminf(fmaxf(v.y, 0.f), 255.f);
        int c = (int)fminf(fmaxf(v.z, 0.f), 255.f);
        int d = (int)fminf(fmaxf(v.w, 0.f), 255.f);
        atomicAdd(&lh[(a << 4) + cp], 1);
        atomicAdd(&lh[(b << 4) + cp], 1);
        atomicAdd(&lh[(c << 4) + cp], 1);
        atomicAdd(&lh[(d << 4) + cp], 1);
    }
    __syncthreads();

    // reduce the 16 copies of bin `tid` (rotated -> 2-way conflicts only)
    int s = 0;
    #pragma unroll
    for (int k = 0; k < NCOPY; ++k) s += lh[(tid << 4) + ((tid + k) & 15)];
    partials[blockIdx.x * NBINS + tid] = s;
}

// Phase B: sum the channel's 8 partials -> Hillis-Steele scan -> exact-int LUT
// (identical to the fp32 reference: all intermediates < 2^24), replicated into
// the (reused) lh buffer. Phase C: re-read strip (L3-resident, proven by round-3
// FETCH_SIZE), gather LUT, nontemporal store.
__device__ __forceinline__ void phaseBC_apply(const float* __restrict__ x,
                                              float* __restrict__ out,
                                              const int* __restrict__ partials,
                                              int* lh, int* scan,
                                              int* s_last_idx, int* s_last) {
    const int chan = blockIdx.x / BPC;
    const int tid  = threadIdx.x;
    const int cp   = (tid & 63) >> 2;

    int h = 0;
    #pragma unroll
    for (int b = 0; b < BPC; ++b)
        h += partials[(chan * BPC + b) * NBINS + tid];
    scan[tid] = h;
    if (tid == 0) *s_last_idx = 0;
    __syncthreads();
    if (h > 0) atomicMax(s_last_idx, tid);

    for (int off = 1; off < NBINS; off <<= 1) {   // inclusive Hillis-Steele scan
        int t = (tid >= off) ? scan[tid - off] : 0;
        __syncthreads();
        scan[tid] += t;
        __syncthreads();
    }
    if (tid == *s_last_idx) *s_last = h;          // count of last nonzero bin
    __syncthreads();

    const int total = scan[NBINS - 1];
    const int step  = (total - *s_last) / 255;    // floor, nonneg

    float lutv;
    if (step == 0)      lutv = (float)tid;        // identity
    else if (tid == 0)  lutv = 0.f;               // shifted-in leading zero
    else {
        int l = (scan[tid - 1] + (step >> 1)) / step;
        lutv = (float)(l < 255 ? l : 255);
    }
    float* slut = (float*)lh;                     // reuse hist LDS for the LUT
    #pragma unroll
    for (int k = 0; k < NCOPY; ++k) slut[(tid << 4) + ((tid + k) & 15)] = lutv;
    __syncthreads();

    const size_t base = (size_t)blockIdx.x * VPB;
    const f4* bx = (const f4*)x + base;
    f4* bo = (f4*)out + base;

    #pragma unroll 4
    for (int i = tid; i < VPB; i += TPB) {
        f4 v = bx[i];                             // L3 hit (round-3 counters)
        int a = (int)fminf(fmaxf(v.x, 0.f), 255.f);
        int b = (int)fminf(fmaxf(v.y, 0.f), 255.f);
        int c = (int)fminf(fmaxf(v.z, 0.f), 255.f);
        int d = (int)fminf(fmaxf(v.w, 0.f), 255.f);
        f4 o;
        o.x = slut[(a << 4) + cp];
        o.y = slut[(b << 4) + cp];
        o.z = slut[(c << 4) + cp];
        o.w = slut[(d << 4) + cp];
        __builtin_nontemporal_store(o, &bo[i]);
    }
}

// Cooperative single-dispatch version: grid 1536 = 6 blocks/CU needed;
// capacity 8/CU (LDS 17.4 KiB, 4 waves, ~40 VGPR) so co-residency holds.
__global__ __launch_bounds__(TPB) void equalize_coop(const float* __restrict__ x,
                                                     float* __restrict__ out,
                                                     int* __restrict__ partials) {
    __shared__ int lh[NBINS * NCOPY];
    __shared__ int scan[NBINS];
    __shared__ int s_last_idx, s_last;
    phaseA_hist(x, partials, lh);
    cg::this_grid().sync();
    phaseBC_apply(x, out, partials, lh, scan, &s_last_idx, &s_last);
}

// Fallback pair (used only if cooperative launch is rejected).
__global__ __launch_bounds__(TPB) void eq_hist(const float* __restrict__ x,
                                               int* __restrict__ partials) {
    __shared__ int lh[NBINS * NCOPY];
    phaseA_hist(x, partials, lh);
}
__global__ __launch_bounds__(TPB) void eq_apply(const float* __restrict__ x,
                                                float* __restrict__ out,
                                                const int* __restrict__ partials) {
    __shared__ int lh[NBINS * NCOPY];
    __shared__ int scan[NBINS];
    __shared__ int s_last_idx, s_last;
    phaseBC_apply(x, out, partials, lh, scan, &s_last_idx, &s_last);
}

extern "C" void kernel_launch(void* const* d_in, const int* in_sizes, int n_in,
                              void* d_out, int out_size, void* d_ws, size_t ws_size,
                              hipStream_t stream) {
    const float* x = (const float*)d_in[0];
    // d_in[1] is `magnitude` — unused by the reference.
    float* out = (float*)d_out;
    int* partials = (int*)d_ws;          // 1536*256*4 = 1.5 MiB

    void* args[] = {(void*)&x, (void*)&out, (void*)&partials};
    hipError_t e = hipLaunchCooperativeKernel((const void*)equalize_coop,
                                              dim3(NCHAN * BPC), dim3(TPB),
                                              args, 0, stream);
    if (e != hipSuccess) {
        eq_hist<<<NCHAN * BPC, TPB, 0, stream>>>(x, partials);
        eq_apply<<<NCHAN * BPC, TPB, 0, stream>>>(x, out, partials);
    }
}

// Round 7
// 458.621 us; speedup vs baseline: 1.1367x; 1.1367x over previous
//
#include <hip/hip_runtime.h>

// Third attempt at the sync-free redundant-histogram design. Rounds 5/6 died
// in infra ("container failed twice", no profile) on byte-identical source;
// audit found no crash/hang mechanism (unconditional barriers, bijective
// block mapping, in-range addresses, LDS-only atomics). Renamed + restructured
// so the binary hash differs; semantics identical.

#define NBINS 256
#define NCHAN 192                 // 64*3 channels
#define BPC 4                     // sibling blocks per channel
#define TPB 256                   // 4 waves/block; grid 768 = 3 blocks/CU
#define NCOPY 32                  // replication: lanes 2k,2k+1 -> copy k -> bank k (2 lanes/bank = free, m136)
#define F4_PER_CHAN 65536         // channel = 1 MiB = 65536 float4
#define F4_PER_STRIP 16384        // quarter strip

typedef float f4 __attribute__((ext_vector_type(4)));

__device__ __forceinline__ int clamp_u8(float v) {
    return (int)fminf(fmaxf(v, 0.f), 255.f);
}

// Design:
//  - 4 sibling blocks per channel, swizzled onto the SAME XCD (bid&7, m09).
//    Each histograms the FULL channel redundantly: first reader fetches from
//    HBM, lockstep siblings hit that XCD's L2/L3 -> HBM fetch stays ~200 MB.
//  - Each block independently copy-reduces + scans -> exact-int LUT
//    (identical to the fp32 reference: all intermediates < 2^24).
//  - Each block applies only its quarter-strip (in-kernel re-read is
//    L3-absorbed, proven by round-3 FETCH_SIZE), nontemporal store.
//  - No grid sync (round-4: ~140us), no flags, no workspace.
__global__ __launch_bounds__(TPB) void eq_hist4_apply(const float* __restrict__ x,
                                                      float* __restrict__ out) {
    __shared__ int lh[NBINS * NCOPY];     // 32 KiB; reused as float LUT later
    __shared__ int scan[NBINS];
    __shared__ int s_last_idx, s_last;

    const int tid = threadIdx.x;
    const int cp  = (tid & 63) >> 1;      // copy/bank id for this lane pair

    // blockIdx swizzle: keep a channel's 4 siblings on one XCD (perf-only).
    const int bid  = blockIdx.x;
    const int xcd  = bid & 7;
    const int slot = bid >> 3;            // 0..95 within this XCD
    const int chan = (slot >> 2) * 8 + xcd;
    const int blk  = slot & 3;

    for (int i = tid; i < NBINS * NCOPY; i += TPB) lh[i] = 0;
    if (tid == 0) s_last_idx = 0;
    __syncthreads();

    // ---- Phase A: full-channel histogram (redundant across siblings) ----
    const f4* cx = (const f4*)x + (size_t)chan * F4_PER_CHAN;
    for (int i = tid; i < F4_PER_CHAN; i += TPB) {
        f4 v = cx[i];
        atomicAdd(&lh[(clamp_u8(v.x) << 5) + cp], 1);
        atomicAdd(&lh[(clamp_u8(v.y) << 5) + cp], 1);
        atomicAdd(&lh[(clamp_u8(v.z) << 5) + cp], 1);
        atomicAdd(&lh[(clamp_u8(v.w) << 5) + cp], 1);
    }
    __syncthreads();

    // ---- Phase B: reduce replicas, scan, build LUT ----
    int h = 0;                             // TPB==NBINS: thread owns bin `tid`
    #pragma unroll
    for (int k = 0; k < NCOPY; ++k) h += lh[(tid << 5) + ((tid + k) & 31)];
    scan[tid] = h;
    __syncthreads();                       // last lh read before reuse as slut
    if (h > 0) atomicMax(&s_last_idx, tid);

    for (int off = 1; off < NBINS; off <<= 1) {    // inclusive Hillis-Steele
        int t = (tid >= off) ? scan[tid - off] : 0;
        __syncthreads();
        scan[tid] += t;
        __syncthreads();
    }
    if (tid == s_last_idx) s_last = h;     // count of last nonzero bin
    __syncthreads();

    const int total = scan[NBINS - 1];
    const int step  = (total - s_last) / 255;      // floor, nonneg

    float lutv;
    if (step == 0)      lutv = (float)tid;         // identity mapping
    else if (tid == 0)  lutv = 0.f;                // shifted-in leading zero
    else {
        int l = (scan[tid - 1] + (step >> 1)) / step;
        lutv = (float)(l < 255 ? l : 255);
    }
    float* slut = (float*)lh;
    #pragma unroll
    for (int k = 0; k < NCOPY; ++k) slut[(tid << 5) + ((tid + k) & 31)] = lutv;
    __syncthreads();

    // ---- Phase C: apply own quarter-strip (L2/L3-warm re-read), nt-store ----
    const size_t sb = (size_t)chan * F4_PER_CHAN + (size_t)blk * F4_PER_STRIP;
    const f4* bx = (const f4*)x + sb;
    f4* bo = (f4*)out + sb;

    for (int i = tid; i < F4_PER_STRIP; i += TPB) {
        f4 v = bx[i];
        f4 o;
        o.x = slut[(clamp_u8(v.x) << 5) + cp];
        o.y = slut[(clamp_u8(v.y) << 5) + cp];
        o.z = slut[(clamp_u8(v.z) << 5) + cp];
        o.w = slut[(clamp_u8(v.w) << 5) + cp];
        __builtin_nontemporal_store(o, &bo[i]);
    }
}

extern "C" void kernel_launch(void* const* d_in, const int* in_sizes, int n_in,
                              void* d_out, int out_size, void* d_ws, size_t ws_size,
                              hipStream_t stream) {
    const float* x = (const float*)d_in[0];
    // d_in[1] is `magnitude` — unused by the reference.
    float* out = (float*)d_out;
    (void)d_ws; (void)ws_size;

    eq_hist4_apply<<<NCHAN * BPC, TPB, 0, stream>>>(x, out);
}

// Round 8
// 341.956 us; speedup vs baseline: 1.5245x; 1.3412x over previous
//
#include <hip/hip_runtime.h>

#define NBINS 256
#define NCHAN 192                 // 64*3 channels
#define BPC 8                     // blocks per channel (both big kernels): grid 1536 -> 6 blocks/CU
#define TPB 256                   // 4 waves/block
#define NCOPY 16                  // bank-replicated LDS copies: lanes 4k..4k+3 -> copy k (~2-way, free per m136)
#define F4_PER_CHAN 65536         // channel = 1 MiB = 65536 float4
#define F4_PER_BLK (F4_PER_CHAN / BPC)   // 8192 float4 per block strip

typedef float f4 __attribute__((ext_vector_type(4)));

// Per-CU-issue-cost model (validated rounds 0/1/3/7): time ~= issued bytes /
// 10.2 B/cyc/CU, independent of cache level. So: minimize TOTAL bytes issued,
// use ALL 256 CUs, no sync. Packed-u8 intermediate: 201(x) + 50(pack W) +
// 50(pack R) + 201(out) = 502 MB -> 80 us floor, vs 603 MB re-read design.

// k1: read x once (nt-load: read-once, don't displace the packed image),
// clamp->u8, pack 4 px/u32, plain-store (cached: k2's input, 50 MB << L3),
// histogram into bank-replicated LDS, plain-store per-block partial.
__global__ __launch_bounds__(TPB) void eq_hist_pack(const float* __restrict__ x,
                                                    unsigned* __restrict__ packed,
                                                    int* __restrict__ partials) {
    __shared__ int lh[NBINS * NCOPY];     // 16 KiB
    const int tid = threadIdx.x;
    const int cp  = (tid & 63) >> 2;

    for (int i = tid; i < NBINS * NCOPY; i += TPB) lh[i] = 0;
    __syncthreads();

    const size_t base = (size_t)blockIdx.x * F4_PER_BLK;
    const f4* bx = (const f4*)x + base;
    unsigned* bp = packed + base;

    for (int i = tid; i < F4_PER_BLK; i += TPB) {
        f4 v = __builtin_nontemporal_load(&bx[i]);
        int a = (int)fminf(fmaxf(v.x, 0.f), 255.f);
        int b = (int)fminf(fmaxf(v.y, 0.f), 255.f);
        int c = (int)fminf(fmaxf(v.z, 0.f), 255.f);
        int d = (int)fminf(fmaxf(v.w, 0.f), 255.f);
        bp[i] = (unsigned)(a | (b << 8) | (c << 16) | (d << 24));
        atomicAdd(&lh[(a << 4) + cp], 1);
        atomicAdd(&lh[(b << 4) + cp], 1);
        atomicAdd(&lh[(c << 4) + cp], 1);
        atomicAdd(&lh[(d << 4) + cp], 1);
    }
    __syncthreads();

    // reduce the 16 copies of bin `tid` (rotated -> 2-way, free)
    int s = 0;
    #pragma unroll
    for (int k = 0; k < NCOPY; ++k) s += lh[(tid << 4) + ((tid + k) & 15)];
    partials[blockIdx.x * NBINS + tid] = s;
}

// k2: one block per channel builds the 256-entry LUT once (exact-int math,
// identical to the fp32 reference: all intermediates < 2^24). Proven in round 1.
__global__ __launch_bounds__(TPB) void eq_lut(const int* __restrict__ partials,
                                              float* __restrict__ lut) {
    __shared__ int scan[NBINS];
    __shared__ int s_last_idx, s_last;
    const int chan = blockIdx.x;
    const int tid  = threadIdx.x;

    int h = 0;
    #pragma unroll
    for (int b = 0; b < BPC; ++b)
        h += partials[(chan * BPC + b) * NBINS + tid];
    scan[tid] = h;
    if (tid == 0) s_last_idx = 0;
    __syncthreads();
    if (h > 0) atomicMax(&s_last_idx, tid);

    for (int off = 1; off < NBINS; off <<= 1) {   // inclusive Hillis-Steele scan
        int t = (tid >= off) ? scan[tid - off] : 0;
        __syncthreads();
        scan[tid] += t;
        __syncthreads();
    }
    if (tid == s_last_idx) s_last = h;            // count of last nonzero bin
    __syncthreads();

    const int total = scan[NBINS - 1];
    const int step  = (total - s_last) / 255;     // floor, nonneg

    float lutv;
    if (step == 0)      lutv = (float)tid;        // identity
    else if (tid == 0)  lutv = 0.f;               // shifted-in leading zero
    else {
        int l = (scan[tid - 1] + (step >> 1)) / step;
        lutv = (float)(l < 255 ? l : 255);
    }
    lut[chan * NBINS + tid] = lutv;
}

// k3: read packed u8 (1 B/px issue; 50 MB, expect heavy L3 hit), gather through
// bank-replicated LDS LUT, nontemporal f4 store of out.
__global__ __launch_bounds__(TPB) void eq_apply(const unsigned* __restrict__ packed,
                                                float* __restrict__ out,
                                                const float* __restrict__ lut) {
    __shared__ float slut[NBINS * NCOPY]; // 16 KiB
    const int chan = blockIdx.x / BPC;
    const int tid  = threadIdx.x;
    const int cp   = (tid & 63) >> 2;

    const float lv = lut[chan * NBINS + tid];
    #pragma unroll
    for (int k = 0; k < NCOPY; ++k) slut[(tid << 4) + ((tid + k) & 15)] = lv;
    __syncthreads();

    const size_t base = (size_t)blockIdx.x * F4_PER_BLK;
    const unsigned* bp = packed + base;
    f4* bo = (f4*)out + base;

    for (int i = tid; i < F4_PER_BLK; i += TPB) {
        unsigned p = bp[i];
        f4 o;
        o.x = slut[(int)((p & 255u) << 4) + cp];
        o.y = slut[(int)(((p >> 8) & 255u) << 4) + cp];
        o.z = slut[(int)(((p >> 16) & 255u) << 4) + cp];
        o.w = slut[(int)((p >> 24) << 4) + cp];
        __builtin_nontemporal_store(o, &bo[i]);
    }
}

extern "C" void kernel_launch(void* const* d_in, const int* in_sizes, int n_in,
                              void* d_out, int out_size, void* d_ws, size_t ws_size,
                              hipStream_t stream) {
    const float* x = (const float*)d_in[0];
    // d_in[1] is `magnitude` — unused by the reference.
    float* out = (float*)d_out;

    // ws layout: [packed u8 image: 192*65536 u32 = 48 MiB][partials: 1.5 MiB][lut: 192 KiB]
    unsigned* packed = (unsigned*)d_ws;
    int* partials = (int*)d_ws + (size_t)NCHAN * F4_PER_CHAN;
    float* lut = (float*)(partials + (size_t)NCHAN * BPC * NBINS);

    eq_hist_pack<<<NCHAN * BPC, TPB, 0, stream>>>(x, packed, partials);
    eq_lut<<<NCHAN, TPB, 0, stream>>>(partials, lut);
    eq_apply<<<NCHAN * BPC, TPB, 0, stream>>>(packed, out, lut);
}